// Round 2
// baseline (787.145 us; speedup 1.0000x reference)
//
#include <hip/hip_runtime.h>

// Problem constants (match reference)
#define D 128
#define H 8
#define DK 16
#define FFDIM 512
#define NTYPES 5
#define LN_EPS 1e-5f

// ---- bf16 helpers (raw bit ops, RNE) --------------------------------------
__device__ inline float bf2f(unsigned short u) {
  return __uint_as_float(((unsigned int)u) << 16);
}
__device__ inline unsigned short f2bf(float f) {
  unsigned int x = __float_as_uint(f);
  return (unsigned short)((x + 0x7FFFu + ((x >> 16) & 1u)) >> 16);
}

// ---------------------------------------------------------------------------
// K0: detect mask dtype. If masks are 1-byte bools, every edge column sums
// to exactly 1 (exact partition). If they are int32, the byte view fails
// (bytes 1..3 of each word are zero). Writes flag=1 for byte-masks.
// ---------------------------------------------------------------------------
__global__ void detect_kernel(const unsigned char* __restrict__ m8, int E,
                              int* __restrict__ flag) {
  if (threadIdx.x == 0 && blockIdx.x == 0) {
    int ok = 1;
    int lim = E < 64 ? E : 64;
    for (int e = 0; e < lim; ++e) {
      int s = 0;
      for (int i = 0; i < NTYPES; ++i) s += (m8[(size_t)i * E + e] != 0);
      if (s != 1) ok = 0;
    }
    *flag = ok;
  }
}

__device__ inline int decode_etype(const unsigned char* __restrict__ m8,
                                   int E, int e, int is8) {
  int t = 0;
  if (is8) {
#pragma unroll
    for (int i = 1; i < NTYPES; ++i) t += i * (m8[(size_t)i * E + e] != 0);
  } else {
    const int* m32 = (const int*)m8;
#pragma unroll
    for (int i = 1; i < NTYPES; ++i) t += i * (m32[(size_t)i * E + e] != 0);
  }
  return t > (NTYPES - 1) ? (NTYPES - 1) : t;  // clamp defensively
}

// ---------------------------------------------------------------------------
// K1: LayerNorm (x -> z), z written into d_out (dead after proj consumes it)
// ---------------------------------------------------------------------------
__global__ __launch_bounds__(256) void ln1_kernel(
    const float* __restrict__ x, const float* __restrict__ g,
    const float* __restrict__ b, float* __restrict__ z, int n) {
  int row = blockIdx.x * 4 + (threadIdx.x >> 6);
  int lane = threadIdx.x & 63;
  if (row >= n) return;
  const float* xr = x + (size_t)row * D;
  float v0 = xr[lane], v1 = xr[lane + 64];
  float s = v0 + v1, ss = v0 * v0 + v1 * v1;
  for (int o = 32; o; o >>= 1) { s += __shfl_xor(s, o); ss += __shfl_xor(ss, o); }
  float mu = s * (1.f / D);
  float var = ss * (1.f / D) - mu * mu;
  float rs = rsqrtf(var + LN_EPS);
  float* zr = z + (size_t)row * D;
  zr[lane]      = (v0 - mu) * rs * g[lane] + b[lane];
  zr[lane + 64] = (v1 - mu) * rs * g[lane + 64] + b[lane + 64];
}

// ---------------------------------------------------------------------------
// K2: P[t][n][d] = bf16( z[n] @ Wk[t] + bk[t] )
// block = 128 threads (thread == output dim d), 32 nodes per block.
// ---------------------------------------------------------------------------
#define TN 32
__global__ __launch_bounds__(128) void proj_kernel(
    const float* __restrict__ z, const float* __restrict__ Wk,
    const float* __restrict__ bk, unsigned short* __restrict__ P, int n) {
  int t = blockIdx.y;
  int n0 = blockIdx.x * TN;
  int d = threadIdx.x;
  __shared__ float zs[TN][D];
  for (int i = 0; i < TN; ++i) {
    int r = n0 + i;
    zs[i][d] = (r < n) ? z[(size_t)r * D + d] : 0.f;
  }
  __syncthreads();
  const float* W = Wk + (size_t)t * D * D;
  float bias = bk[t * D + d];
  float acc[TN];
#pragma unroll
  for (int i = 0; i < TN; ++i) acc[i] = 0.f;
  for (int k = 0; k < D; k += 4) {
    float w0 = W[(k + 0) * D + d];
    float w1 = W[(k + 1) * D + d];
    float w2 = W[(k + 2) * D + d];
    float w3 = W[(k + 3) * D + d];
#pragma unroll
    for (int i = 0; i < TN; ++i) {
      float4 zv = *(const float4*)&zs[i][k];
      acc[i] += zv.x * w0 + zv.y * w1 + zv.z * w2 + zv.w * w3;
    }
  }
  unsigned short* Pt = P + ((size_t)t * n + n0) * D;
  for (int i = 0; i < TN; ++i) {
    if (n0 + i < n) Pt[(size_t)i * D + d] = f2bf(acc[i] + bias);
  }
}

// ---------------------------------------------------------------------------
// K3: CSR build by src
// ---------------------------------------------------------------------------
__global__ void zero_kernel(int* __restrict__ p, int n) {
  int i = blockIdx.x * 256 + threadIdx.x;
  if (i < n) p[i] = 0;
}

__global__ void hist_kernel(const int* __restrict__ edges,
                            int* __restrict__ cnt, int E) {
  int e = blockIdx.x * 256 + threadIdx.x;
  if (e >= E) return;
  atomicAdd(&cnt[edges[e]], 1);  // src
}

// single block, 1024 threads: exclusive scan cnt -> offs[0..n], cursor = offs
__global__ __launch_bounds__(1024) void scan_kernel(const int* __restrict__ cnt,
                                                    int* __restrict__ offs,
                                                    int* __restrict__ cursor,
                                                    int n) {
  __shared__ int sums[1024];
  int tid = threadIdx.x;
  int per = (n + 1023) / 1024;
  int start = tid * per;
  int end = min(start + per, n);
  int s = 0;
  for (int i = start; i < end; ++i) s += cnt[i];
  sums[tid] = s;
  __syncthreads();
  for (int o = 1; o < 1024; o <<= 1) {
    int v = (tid >= o) ? sums[tid - o] : 0;
    __syncthreads();
    sums[tid] += v;
    __syncthreads();
  }
  int base = sums[tid] - s;  // exclusive prefix
  for (int i = start; i < end; ++i) {
    offs[i] = base;
    cursor[i] = base;
    base += cnt[i];
  }
  if (tid == 1023) offs[n] = sums[1023];
}

// fill packed edge list: elist[pos] = (etype << 29) | dst, grouped by src
__global__ void fill_kernel(const int* __restrict__ edges,
                            const unsigned char* __restrict__ masks,
                            const int* __restrict__ flag,
                            int* __restrict__ cursor,
                            unsigned int* __restrict__ elist, int E) {
  int e = blockIdx.x * 256 + threadIdx.x;
  if (e >= E) return;
  int is8 = *flag;
  int t = decode_etype(masks, E, e, is8);
  int dst = edges[E + e];
  int pos = atomicAdd(&cursor[edges[e]], 1);
  elist[pos] = ((unsigned int)t << 29) | (unsigned int)(dst & 0x1FFFFFFF);
}

// ---------------------------------------------------------------------------
// K4: per-node attention (one wave per node, 2 dims/lane, head = lane/8)
// writes x2 = x + attn into out  (overwrites the z that was parked there)
// ---------------------------------------------------------------------------
__global__ __launch_bounds__(256) void attn_kernel(
    const float* __restrict__ x, const unsigned short* __restrict__ P,
    const int* __restrict__ offs, const unsigned int* __restrict__ elist,
    float* __restrict__ out, int n) {
  int node = blockIdx.x * 4 + (threadIdx.x >> 6);
  int lane = threadIdx.x & 63;
  if (node >= n) return;

  // preload q rows for all 5 types (2 bf16/lane each)
  float q0[NTYPES], q1[NTYPES];
#pragma unroll
  for (int t = 0; t < NTYPES; ++t) {
    unsigned int qw = *(const unsigned int*)(P + ((size_t)t * n + node) * D + 2 * lane);
    q0[t] = bf2f((unsigned short)(qw & 0xFFFFu));
    q1[t] = bf2f((unsigned short)(qw >> 16));
  }

  float m = -1e30f, den = 0.f, a0 = 0.f, a1 = 0.f;
  int beg = offs[node], end = offs[node + 1];
  for (int j = beg; j < end; ++j) {
    unsigned int pv = elist[j];
    int t = pv >> 29;
    int dst = pv & 0x1FFFFFFF;
    unsigned int kw = *(const unsigned int*)(P + ((size_t)t * n + dst) * D + 2 * lane);
    float k0 = bf2f((unsigned short)(kw & 0xFFFFu));
    float k1 = bf2f((unsigned short)(kw >> 16));
    float qa = (t == 0) ? q0[0] : (t == 1) ? q0[1] : (t == 2) ? q0[2] : (t == 3) ? q0[3] : q0[4];
    float qb = (t == 0) ? q1[0] : (t == 1) ? q1[1] : (t == 2) ? q1[2] : (t == 3) ? q1[3] : q1[4];
    float p = qa * k0 + qb * k1;
    // reduce over the 8 lanes of this head (dims 16h..16h+15 <-> lanes 8h..8h+7)
    p += __shfl_xor(p, 1);
    p += __shfl_xor(p, 2);
    p += __shfl_xor(p, 4);
    float newm = fmaxf(m, p);
    float scale = __expf(m - newm);
    float w = __expf(p - newm);
    den = den * scale + w;
    a0 = a0 * scale + w * k0;
    a1 = a1 * scale + w * k1;
    m = newm;
  }
  float inv = (end > beg) ? 1.f / den : 0.f;
  const float* xr = x + (size_t)node * D;
  float* orow = out + (size_t)node * D;
  orow[2 * lane]     = xr[2 * lane]     + a0 * inv;
  orow[2 * lane + 1] = xr[2 * lane + 1] + a1 * inv;
}

// ---------------------------------------------------------------------------
// K5: fused LN2 + FFN + residual, in-place on out (which holds x2)
// 16 nodes per block, 256 threads. LDS: z2 (8KB) + H (32KB).
// ---------------------------------------------------------------------------
#define FF_TM 16
__global__ __launch_bounds__(256) void ffn_kernel(
    const float* __restrict__ W1, const float* __restrict__ b1,
    const float* __restrict__ W2, const float* __restrict__ b2,
    const float* __restrict__ g, const float* __restrict__ bln,
    float* __restrict__ out, int n) {
  __shared__ float z2s[FF_TM][D];
  __shared__ float hs[FF_TM][FFDIM];
  int n0 = blockIdx.x * FF_TM;
  int tid = threadIdx.x;
  int wv = tid >> 6, lane = tid & 63;

  // Phase 0: LN2 of 16 rows (4 waves x 4 rows)
  for (int i = wv; i < FF_TM; i += 4) {
    int r = n0 + i;
    float v0 = 0.f, v1 = 0.f;
    if (r < n) {
      v0 = out[(size_t)r * D + lane];
      v1 = out[(size_t)r * D + 64 + lane];
    }
    float s = v0 + v1, ss = v0 * v0 + v1 * v1;
    for (int o = 32; o; o >>= 1) { s += __shfl_xor(s, o); ss += __shfl_xor(ss, o); }
    float mu = s * (1.f / D);
    float var = ss * (1.f / D) - mu * mu;
    float rs = rsqrtf(var + LN_EPS);
    z2s[i][lane]      = (v0 - mu) * rs * g[lane] + bln[lane];
    z2s[i][lane + 64] = (v1 - mu) * rs * g[lane + 64] + bln[lane + 64];
  }
  __syncthreads();

  // Phase 1: H = relu(z2 @ W1 + b1); thread covers hidden cols tid, tid+256
  float acc[FF_TM][2];
#pragma unroll
  for (int i = 0; i < FF_TM; ++i) { acc[i][0] = 0.f; acc[i][1] = 0.f; }
  for (int k = 0; k < D; k += 4) {
    float w00 = W1[(k + 0) * FFDIM + tid], w01 = W1[(k + 0) * FFDIM + tid + 256];
    float w10 = W1[(k + 1) * FFDIM + tid], w11 = W1[(k + 1) * FFDIM + tid + 256];
    float w20 = W1[(k + 2) * FFDIM + tid], w21 = W1[(k + 2) * FFDIM + tid + 256];
    float w30 = W1[(k + 3) * FFDIM + tid], w31 = W1[(k + 3) * FFDIM + tid + 256];
#pragma unroll
    for (int i = 0; i < FF_TM; ++i) {
      float4 zv = *(const float4*)&z2s[i][k];
      acc[i][0] += zv.x * w00 + zv.y * w10 + zv.z * w20 + zv.w * w30;
      acc[i][1] += zv.x * w01 + zv.y * w11 + zv.z * w21 + zv.w * w31;
    }
  }
  float bb0 = b1[tid], bb1 = b1[tid + 256];
#pragma unroll
  for (int i = 0; i < FF_TM; ++i) {
    hs[i][tid]       = fmaxf(acc[i][0] + bb0, 0.f);
    hs[i][tid + 256] = fmaxf(acc[i][1] + bb1, 0.f);
  }
  __syncthreads();

  // Phase 2: out += H @ W2 + b2 ; thread covers dim d for 8 rows
  int d = tid & 127, half = tid >> 7;
  float acc2[8];
#pragma unroll
  for (int i = 0; i < 8; ++i) acc2[i] = 0.f;
  for (int j = 0; j < FFDIM; j += 4) {
    float w0 = W2[(j + 0) * D + d];
    float w1 = W2[(j + 1) * D + d];
    float w2 = W2[(j + 2) * D + d];
    float w3 = W2[(j + 3) * D + d];
#pragma unroll
    for (int i = 0; i < 8; ++i) {
      float4 hv = *(const float4*)&hs[half * 8 + i][j];
      acc2[i] += hv.x * w0 + hv.y * w1 + hv.z * w2 + hv.w * w3;
    }
  }
  float bd = b2[d];
#pragma unroll
  for (int i = 0; i < 8; ++i) {
    int r = n0 + half * 8 + i;
    if (r < n) {
      size_t o = (size_t)r * D + d;
      out[o] = out[o] + acc2[i] + bd;
    }
  }
}

// ---------------------------------------------------------------------------
extern "C" void kernel_launch(void* const* d_in, const int* in_sizes, int n_in,
                              void* d_out, int out_size, void* d_ws, size_t ws_size,
                              hipStream_t stream) {
  const float* x      = (const float*)d_in[0];
  const int* edges    = (const int*)d_in[1];
  const unsigned char* masks = (const unsigned char*)d_in[2];
  const float* Wk     = (const float*)d_in[3];
  const float* bk     = (const float*)d_in[4];
  const float* ln1_g  = (const float*)d_in[5];
  const float* ln1_b  = (const float*)d_in[6];
  const float* ln2_g  = (const float*)d_in[7];
  const float* ln2_b  = (const float*)d_in[8];
  const float* W1     = (const float*)d_in[9];
  const float* b1     = (const float*)d_in[10];
  const float* W2     = (const float*)d_in[11];
  const float* b2     = (const float*)d_in[12];
  float* out = (float*)d_out;

  const int n = in_sizes[0] / D;
  const int E = in_sizes[1] / 2;

  // workspace layout (~68 MB total)
  char* ws = (char*)d_ws;
  size_t off = 0;
  unsigned short* P = (unsigned short*)(ws + off); off += (size_t)NTYPES * n * D * sizeof(unsigned short);
  int* cnt    = (int*)(ws + off);          off += (size_t)n * sizeof(int);
  int* offs   = (int*)(ws + off);          off += (size_t)(n + 1) * sizeof(int);
  int* cursor = (int*)(ws + off);          off += (size_t)n * sizeof(int);
  unsigned int* elist = (unsigned int*)(ws + off); off += (size_t)E * sizeof(unsigned int);
  int* flag   = (int*)(ws + off);          off += 64;
  (void)ws_size; (void)n_in; (void)out_size;

  // K0: mask dtype detection
  detect_kernel<<<1, 64, 0, stream>>>(masks, E, flag);

  // K1: LN1 -> z parked in d_out
  ln1_kernel<<<(n + 3) / 4, 256, 0, stream>>>(x, ln1_g, ln1_b, out, n);

  // K2: projections P[t] = bf16(z @ Wk[t] + bk[t])
  {
    dim3 grid((n + TN - 1) / TN, NTYPES);
    proj_kernel<<<grid, 128, 0, stream>>>(out, Wk, bk, P, n);
  }

  // K3: CSR build by src
  zero_kernel<<<(n + 255) / 256, 256, 0, stream>>>(cnt, n);
  hist_kernel<<<(E + 255) / 256, 256, 0, stream>>>(edges, cnt, E);
  scan_kernel<<<1, 1024, 0, stream>>>(cnt, offs, cursor, n);
  fill_kernel<<<(E + 255) / 256, 256, 0, stream>>>(edges, masks, flag, cursor, elist, E);

  // K4: attention -> out = x + attn
  attn_kernel<<<(n + 3) / 4, 256, 0, stream>>>(x, P, offs, elist, out, n);

  // K5: LN2 + FFN + residual, in place on out
  ffn_kernel<<<(n + FF_TM - 1) / FF_TM, 256, 0, stream>>>(W1, b1, W2, b2, ln2_g, ln2_b, out, n);
}

// Round 3
// 557.381 us; speedup vs baseline: 1.4122x; 1.4122x over previous
//
#include <hip/hip_runtime.h>

// Problem constants (match reference)
#define D 128
#define H 8
#define DK 16
#define FFDIM 512
#define NTYPES 5
#define LN_EPS 1e-5f

typedef __bf16 bf16x8 __attribute__((ext_vector_type(8)));
typedef float f32x4 __attribute__((ext_vector_type(4)));
typedef unsigned short ushort_t;
typedef unsigned int uint_t;

__device__ inline ushort_t bfbits(float f) {
  __bf16 b = (__bf16)f;
  return __builtin_bit_cast(ushort_t, b);
}
__device__ inline float bf2f(ushort_t u) {
  return __uint_as_float(((uint_t)u) << 16);
}

// ---------------------------------------------------------------------------
// K0: detect mask dtype (byte-bool vs int32). flag=1 for byte masks.
// ---------------------------------------------------------------------------
__global__ void detect_kernel(const unsigned char* __restrict__ m8, int E,
                              int* __restrict__ flag) {
  if (threadIdx.x == 0 && blockIdx.x == 0) {
    int ok = 1;
    int lim = E < 64 ? E : 64;
    for (int e = 0; e < lim; ++e) {
      int s = 0;
      for (int i = 0; i < NTYPES; ++i) s += (m8[(size_t)i * E + e] != 0);
      if (s != 1) ok = 0;
    }
    *flag = ok;
  }
}

__device__ inline int decode_etype(const unsigned char* __restrict__ m8,
                                   int E, int e, int is8) {
  int t = 0;
  if (is8) {
#pragma unroll
    for (int i = 1; i < NTYPES; ++i) t += i * (m8[(size_t)i * E + e] != 0);
  } else {
    const int* m32 = (const int*)m8;
#pragma unroll
    for (int i = 1; i < NTYPES; ++i) t += i * (m32[(size_t)i * E + e] != 0);
  }
  return t > (NTYPES - 1) ? (NTYPES - 1) : t;
}

// ---------------------------------------------------------------------------
// K1: LayerNorm x -> z, stored as hi/lo bf16 split (parked in d_out)
// ---------------------------------------------------------------------------
__global__ __launch_bounds__(256) void ln1_kernel(
    const float* __restrict__ x, const float* __restrict__ g,
    const float* __restrict__ b, ushort_t* __restrict__ zh,
    ushort_t* __restrict__ zl, int n) {
  int row = blockIdx.x * 4 + (threadIdx.x >> 6);
  int lane = threadIdx.x & 63;
  if (row >= n) return;
  const float* xr = x + (size_t)row * D;
  float v0 = xr[lane], v1 = xr[lane + 64];
  float s = v0 + v1, ss = v0 * v0 + v1 * v1;
  for (int o = 32; o; o >>= 1) { s += __shfl_xor(s, o); ss += __shfl_xor(ss, o); }
  float mu = s * (1.f / D);
  float var = ss * (1.f / D) - mu * mu;
  float rs = rsqrtf(var + LN_EPS);
  float z0 = (v0 - mu) * rs * g[lane] + b[lane];
  float z1 = (v1 - mu) * rs * g[lane + 64] + b[lane + 64];
  size_t o0 = (size_t)row * D + lane, o1 = o0 + 64;
  __bf16 h0 = (__bf16)z0, h1 = (__bf16)z1;
  zh[o0] = __builtin_bit_cast(ushort_t, h0);
  zh[o1] = __builtin_bit_cast(ushort_t, h1);
  __bf16 l0 = (__bf16)(z0 - (float)h0), l1 = (__bf16)(z1 - (float)h1);
  zl[o0] = __builtin_bit_cast(ushort_t, l0);
  zl[o1] = __builtin_bit_cast(ushort_t, l1);
}

// ---------------------------------------------------------------------------
// K1b: convert a row-major f32 weight [K][N] into MFMA B-fragment order,
// hi/lo bf16 split.  frag[((c*(K/32)+kk)*64 + lane)*8 + j] =
//   W[kk*32 + (lane>>4)*8 + j][c*16 + (lane&15)]
// grid.y = matrix index (stride matW / matF)
// ---------------------------------------------------------------------------
__global__ void conv_frag_kernel(const float* __restrict__ W,
                                 ushort_t* __restrict__ hi,
                                 ushort_t* __restrict__ lo,
                                 int K, int Ncol, size_t matW, size_t matF) {
  int gid = blockIdx.x * 256 + threadIdx.x;
  int total = (Ncol / 16) * (K / 32) * 64;
  if (gid >= total) return;
  const float* Wm = W + (size_t)blockIdx.y * matW;
  ushort_t* him = hi + (size_t)blockIdx.y * matF;
  ushort_t* lom = lo + (size_t)blockIdx.y * matF;
  int l = gid & 63;
  int ck = gid >> 6;
  int kk = ck % (K / 32);
  int c = ck / (K / 32);
  int row0 = kk * 32 + (l >> 4) * 8;
  int col = c * 16 + (l & 15);
  size_t ob = (size_t)gid * 8;
#pragma unroll
  for (int j = 0; j < 8; ++j) {
    float w = Wm[(size_t)(row0 + j) * Ncol + col];
    __bf16 h = (__bf16)w;
    him[ob + j] = __builtin_bit_cast(ushort_t, h);
    __bf16 lo_ = (__bf16)(w - (float)h);
    lom[ob + j] = __builtin_bit_cast(ushort_t, lo_);
  }
}

// ---------------------------------------------------------------------------
// K2: proj via MFMA: P[t][node][d] = bf16( z @ Wk[t] + bk[t] )
// block = 256 (4 waves), 64 rows/block, wave owns 16 rows x 128 cols.
// ---------------------------------------------------------------------------
__global__ __launch_bounds__(256) void proj_mfma_kernel(
    const ushort_t* __restrict__ zh, const ushort_t* __restrict__ zl,
    const ushort_t* __restrict__ wkh, const ushort_t* __restrict__ wkl,
    const float* __restrict__ bk, ushort_t* __restrict__ P, int n) {
  int w = threadIdx.x >> 6, l = threadIdx.x & 63;
  int n0 = blockIdx.x * 64 + w * 16;
  int arow = n0 + (l & 15);
  if (arow >= n) arow = n - 1;
  int koff = (l >> 4) * 8;
  bf16x8 ah[4], al[4];
#pragma unroll
  for (int kk = 0; kk < 4; ++kk) {
    size_t zo = (size_t)arow * D + kk * 32 + koff;
    ah[kk] = *(const bf16x8*)(zh + zo);
    al[kk] = *(const bf16x8*)(zl + zo);
  }
  int col16 = l & 15, rgrp = (l >> 4) * 4;
  for (int t = 0; t < NTYPES; ++t) {
    const ushort_t* bh0 = wkh + (size_t)t * (D * D);
    const ushort_t* bl0 = wkl + (size_t)t * (D * D);
    ushort_t* Pt = P + (size_t)t * n * D;
#pragma unroll
    for (int c = 0; c < 8; ++c) {
      float bias = bk[t * D + c * 16 + col16];
      f32x4 acc = {bias, bias, bias, bias};
#pragma unroll
      for (int kk = 0; kk < 4; ++kk) {
        bf16x8 bh = *(const bf16x8*)(bh0 + ((size_t)(c * 4 + kk) * 64 + l) * 8);
        bf16x8 bl = *(const bf16x8*)(bl0 + ((size_t)(c * 4 + kk) * 64 + l) * 8);
        acc = __builtin_amdgcn_mfma_f32_16x16x32_bf16(ah[kk], bh, acc, 0, 0, 0);
        acc = __builtin_amdgcn_mfma_f32_16x16x32_bf16(ah[kk], bl, acc, 0, 0, 0);
        acc = __builtin_amdgcn_mfma_f32_16x16x32_bf16(al[kk], bh, acc, 0, 0, 0);
      }
#pragma unroll
      for (int r = 0; r < 4; ++r) {
        int row = n0 + rgrp + r;
        if (row < n) Pt[(size_t)row * D + c * 16 + col16] = bfbits(acc[r]);
      }
    }
  }
}

// ---------------------------------------------------------------------------
// K3: CSR build by src
// ---------------------------------------------------------------------------
__global__ void zero_kernel(int* __restrict__ p, int n) {
  int i = blockIdx.x * 256 + threadIdx.x;
  if (i < n) p[i] = 0;
}

__global__ void hist_kernel(const int* __restrict__ edges,
                            int* __restrict__ cnt, int E) {
  int e = blockIdx.x * 256 + threadIdx.x;
  if (e >= E) return;
  atomicAdd(&cnt[edges[e]], 1);
}

__global__ __launch_bounds__(1024) void scan_kernel(const int* __restrict__ cnt,
                                                    int* __restrict__ offs,
                                                    int* __restrict__ cursor,
                                                    int n) {
  __shared__ int sums[1024];
  int tid = threadIdx.x;
  int per = (n + 1023) / 1024;
  int start = tid * per;
  int end = min(start + per, n);
  int s = 0;
  for (int i = start; i < end; ++i) s += cnt[i];
  sums[tid] = s;
  __syncthreads();
  for (int o = 1; o < 1024; o <<= 1) {
    int v = (tid >= o) ? sums[tid - o] : 0;
    __syncthreads();
    sums[tid] += v;
    __syncthreads();
  }
  int base = sums[tid] - s;
  for (int i = start; i < end; ++i) {
    offs[i] = base;
    cursor[i] = base;
    base += cnt[i];
  }
  if (tid == 1023) offs[n] = sums[1023];
}

__global__ void fill_kernel(const int* __restrict__ edges,
                            const unsigned char* __restrict__ masks,
                            const int* __restrict__ flag,
                            int* __restrict__ cursor,
                            uint_t* __restrict__ elist, int E) {
  int e = blockIdx.x * 256 + threadIdx.x;
  if (e >= E) return;
  int is8 = *flag;
  int t = decode_etype(masks, E, e, is8);
  int dst = edges[E + e];
  int pos = atomicAdd(&cursor[edges[e]], 1);
  elist[pos] = ((uint_t)t << 29) | (uint_t)(dst & 0x1FFFFFFF);
}

// ---------------------------------------------------------------------------
// K4: per-node attention, one wave/node, prefetched edge loop.
// writes x2 = x + attn into out (overwrites parked z).
// ---------------------------------------------------------------------------
__global__ __launch_bounds__(256) void attn_kernel(
    const float* __restrict__ x, const ushort_t* __restrict__ P,
    const int* __restrict__ offs, const uint_t* __restrict__ elist,
    float* __restrict__ out, int n) {
  int node = blockIdx.x * 4 + (threadIdx.x >> 6);
  int lane = threadIdx.x & 63;
  if (node >= n) return;

  float q0[NTYPES], q1[NTYPES];
#pragma unroll
  for (int t = 0; t < NTYPES; ++t) {
    uint_t qw = *(const uint_t*)(P + ((size_t)t * n + node) * D + 2 * lane);
    q0[t] = bf2f((ushort_t)(qw & 0xFFFFu));
    q1[t] = bf2f((ushort_t)(qw >> 16));
  }

  float m = -1e30f, den = 0.f, a0 = 0.f, a1 = 0.f;
  int beg = offs[node], end = offs[node + 1];

  uint_t pv = 0, kw = 0;
  if (beg < end) {
    pv = elist[beg];
    int t = pv >> 29, dst = pv & 0x1FFFFFFF;
    kw = *(const uint_t*)(P + ((size_t)t * n + dst) * D + 2 * lane);
  }
  for (int j = beg; j < end; ++j) {
    uint_t pv_n = 0, kw_n = 0;
    if (j + 1 < end) {
      pv_n = elist[j + 1];
      int tn = pv_n >> 29, dn = pv_n & 0x1FFFFFFF;
      kw_n = *(const uint_t*)(P + ((size_t)tn * n + dn) * D + 2 * lane);
    }
    int t = pv >> 29;
    float k0 = bf2f((ushort_t)(kw & 0xFFFFu));
    float k1 = bf2f((ushort_t)(kw >> 16));
    float qa = (t == 0) ? q0[0] : (t == 1) ? q0[1] : (t == 2) ? q0[2] : (t == 3) ? q0[3] : q0[4];
    float qb = (t == 0) ? q1[0] : (t == 1) ? q1[1] : (t == 2) ? q1[2] : (t == 3) ? q1[3] : q1[4];
    float p = qa * k0 + qb * k1;
    p += __shfl_xor(p, 1);
    p += __shfl_xor(p, 2);
    p += __shfl_xor(p, 4);
    float newm = fmaxf(m, p);
    float scale = __expf(m - newm);
    float wgt = __expf(p - newm);
    den = den * scale + wgt;
    a0 = a0 * scale + wgt * k0;
    a1 = a1 * scale + wgt * k1;
    m = newm;
    pv = pv_n;
    kw = kw_n;
  }
  float inv = (end > beg) ? 1.f / den : 0.f;
  const float* xr = x + (size_t)node * D;
  float* orow = out + (size_t)node * D;
  orow[2 * lane]     = xr[2 * lane]     + a0 * inv;
  orow[2 * lane + 1] = xr[2 * lane + 1] + a1 * inv;
}

// ---------------------------------------------------------------------------
// K5: fused LN2 + FFN + residual via MFMA, in-place on out (holds x2).
// 64 rows/block, 4 waves. z2 hi/lo in XOR-swizzled LDS; Hm chunked through
// a padded per-wave LDS bounce tile to re-fragment for the 2nd GEMM.
// ---------------------------------------------------------------------------
__global__ __launch_bounds__(256) void ffn_mfma_kernel(
    const ushort_t* __restrict__ w1h, const ushort_t* __restrict__ w1l,
    const ushort_t* __restrict__ w2h, const ushort_t* __restrict__ w2l,
    const float* __restrict__ b1, const float* __restrict__ b2,
    const float* __restrict__ g, const float* __restrict__ bln,
    float* __restrict__ out, int n) {
  __shared__ ushort_t z2h[64 * D];
  __shared__ ushort_t z2l[64 * D];
  __shared__ float hmb[4][16 * 40];  // per-wave bounce, pad 40 (160B rows)
  int tid = threadIdx.x, w = tid >> 6, l = tid & 63;
  int n0 = blockIdx.x * 64;

  // Phase 0: LN2, write z2 hi/lo into swizzled LDS
  for (int i = w; i < 64; i += 4) {
    int r = n0 + i;
    float v0 = 0.f, v1 = 0.f;
    if (r < n) {
      v0 = out[(size_t)r * D + l];
      v1 = out[(size_t)r * D + 64 + l];
    }
    float s = v0 + v1, ss = v0 * v0 + v1 * v1;
    for (int o = 32; o; o >>= 1) { s += __shfl_xor(s, o); ss += __shfl_xor(ss, o); }
    float mu = s * (1.f / D);
    float var = ss * (1.f / D) - mu * mu;
    float rs = rsqrtf(var + LN_EPS);
    float z0 = (v0 - mu) * rs * g[l] + bln[l];
    float z1 = (v1 - mu) * rs * g[l + 64] + bln[l + 64];
    int sw = (i & 7) << 3;  // element-index XOR (bits 3..5 == byte bits 4..6)
    int e0 = (i * D + l) ^ sw;
    int e1 = (i * D + l + 64) ^ sw;
    __bf16 h0 = (__bf16)z0, h1 = (__bf16)z1;
    z2h[e0] = __builtin_bit_cast(ushort_t, h0);
    z2h[e1] = __builtin_bit_cast(ushort_t, h1);
    __bf16 l0 = (__bf16)(z0 - (float)h0), l1 = (__bf16)(z1 - (float)h1);
    z2l[e0] = __builtin_bit_cast(ushort_t, l0);
    z2l[e1] = __builtin_bit_cast(ushort_t, l1);
  }
  __syncthreads();

  // A-fragments of z2 for this wave (16 rows)
  int lrow = w * 16 + (l & 15);
  int koff = (l >> 4) * 8;
  bf16x8 ah[4], al[4];
#pragma unroll
  for (int kk = 0; kk < 4; ++kk) {
    int e = (lrow * D + kk * 32 + koff) ^ ((lrow & 7) << 3);
    ah[kk] = *(const bf16x8*)(z2h + e);
    al[kk] = *(const bf16x8*)(z2l + e);
  }

  int col16 = l & 15, rgrp = (l >> 4) * 4;
  f32x4 acc2[8];
#pragma unroll
  for (int c = 0; c < 8; ++c) acc2[c] = (f32x4){0.f, 0.f, 0.f, 0.f};
  float* hb = hmb[w];

  for (int kk2 = 0; kk2 < 16; ++kk2) {
    // compute Hm chunk: cols kk2*32 .. +31  (two 16-col tiles)
#pragma unroll
    for (int cc = 0; cc < 2; ++cc) {
      int c = kk2 * 2 + cc;
      float bias = b1[c * 16 + col16];
      f32x4 hacc = {bias, bias, bias, bias};
#pragma unroll
      for (int kk = 0; kk < 4; ++kk) {
        bf16x8 bh = *(const bf16x8*)(w1h + ((size_t)(c * 4 + kk) * 64 + l) * 8);
        bf16x8 bl = *(const bf16x8*)(w1l + ((size_t)(c * 4 + kk) * 64 + l) * 8);
        hacc = __builtin_amdgcn_mfma_f32_16x16x32_bf16(ah[kk], bh, hacc, 0, 0, 0);
        hacc = __builtin_amdgcn_mfma_f32_16x16x32_bf16(ah[kk], bl, hacc, 0, 0, 0);
        hacc = __builtin_amdgcn_mfma_f32_16x16x32_bf16(al[kk], bh, hacc, 0, 0, 0);
      }
#pragma unroll
      for (int r = 0; r < 4; ++r)
        hb[(rgrp + r) * 40 + cc * 16 + col16] = fmaxf(hacc[r], 0.f);
    }
    // re-fragment: lane holds Hm[row=l&15][k = kk2*32 + koff + j]
    float av[8];
    *(float4*)&av[0] = *(const float4*)&hb[(l & 15) * 40 + koff];
    *(float4*)&av[4] = *(const float4*)&hb[(l & 15) * 40 + koff + 4];
    bf16x8 a2h, a2l;
#pragma unroll
    for (int j = 0; j < 8; ++j) {
      __bf16 hv = (__bf16)av[j];
      a2h[j] = hv;
      a2l[j] = (__bf16)(av[j] - (float)hv);
    }
#pragma unroll
    for (int c2 = 0; c2 < 8; ++c2) {
      bf16x8 bh = *(const bf16x8*)(w2h + ((size_t)(c2 * 16 + kk2) * 64 + l) * 8);
      bf16x8 bl = *(const bf16x8*)(w2l + ((size_t)(c2 * 16 + kk2) * 64 + l) * 8);
      acc2[c2] = __builtin_amdgcn_mfma_f32_16x16x32_bf16(a2h, bh, acc2[c2], 0, 0, 0);
      acc2[c2] = __builtin_amdgcn_mfma_f32_16x16x32_bf16(a2h, bl, acc2[c2], 0, 0, 0);
      acc2[c2] = __builtin_amdgcn_mfma_f32_16x16x32_bf16(a2l, bh, acc2[c2], 0, 0, 0);
    }
  }

  // Epilogue: out += ff + b2
#pragma unroll
  for (int c2 = 0; c2 < 8; ++c2) {
    float bias2 = b2[c2 * 16 + col16];
#pragma unroll
    for (int r = 0; r < 4; ++r) {
      int row = n0 + w * 16 + rgrp + r;
      if (row < n) {
        size_t o = (size_t)row * D + c2 * 16 + col16;
        out[o] = out[o] + acc2[c2][r] + bias2;
      }
    }
  }
}

// ---------------------------------------------------------------------------
extern "C" void kernel_launch(void* const* d_in, const int* in_sizes, int n_in,
                              void* d_out, int out_size, void* d_ws, size_t ws_size,
                              hipStream_t stream) {
  const float* x      = (const float*)d_in[0];
  const int* edges    = (const int*)d_in[1];
  const unsigned char* masks = (const unsigned char*)d_in[2];
  const float* Wk     = (const float*)d_in[3];
  const float* bk     = (const float*)d_in[4];
  const float* ln1_g  = (const float*)d_in[5];
  const float* ln1_b  = (const float*)d_in[6];
  const float* ln2_g  = (const float*)d_in[7];
  const float* ln2_b  = (const float*)d_in[8];
  const float* W1     = (const float*)d_in[9];
  const float* b1     = (const float*)d_in[10];
  const float* W2     = (const float*)d_in[11];
  const float* b2     = (const float*)d_in[12];
  float* out = (float*)d_out;

  const int n = in_sizes[0] / D;
  const int E = in_sizes[1] / 2;

  // workspace layout (~68.7 MB)
  char* ws = (char*)d_ws;
  size_t off = 0;
  ushort_t* P = (ushort_t*)(ws + off);  off += (size_t)NTYPES * n * D * sizeof(ushort_t);
  int* cnt    = (int*)(ws + off);       off += (size_t)n * sizeof(int);
  int* offs   = (int*)(ws + off);       off += (size_t)(n + 1) * sizeof(int);
  int* cursor = (int*)(ws + off);       off += (size_t)n * sizeof(int);
  uint_t* elist = (uint_t*)(ws + off);  off += (size_t)E * sizeof(uint_t);
  int* flag   = (int*)(ws + off);       off += 64;
  ushort_t* wkh = (ushort_t*)(ws + off); off += (size_t)NTYPES * D * D * sizeof(ushort_t);
  ushort_t* wkl = (ushort_t*)(ws + off); off += (size_t)NTYPES * D * D * sizeof(ushort_t);
  ushort_t* w1h = (ushort_t*)(ws + off); off += (size_t)D * FFDIM * sizeof(ushort_t);
  ushort_t* w1l = (ushort_t*)(ws + off); off += (size_t)D * FFDIM * sizeof(ushort_t);
  ushort_t* w2h = (ushort_t*)(ws + off); off += (size_t)FFDIM * D * sizeof(ushort_t);
  ushort_t* w2l = (ushort_t*)(ws + off); off += (size_t)FFDIM * D * sizeof(ushort_t);
  (void)ws_size; (void)n_in; (void)out_size;

  // z hi/lo parked in d_out (dead before attn writes x2 there)
  ushort_t* zh = (ushort_t*)out;
  ushort_t* zl = zh + (size_t)n * D;

  // K0: mask dtype detection
  detect_kernel<<<1, 64, 0, stream>>>(masks, E, flag);

  // K1: LN1 -> z hi/lo
  ln1_kernel<<<(n + 3) / 4, 256, 0, stream>>>(x, ln1_g, ln1_b, zh, zl, n);

  // K1b: weight fragment conversion
  {
    dim3 gwk((8 * 4 * 64 + 255) / 256, NTYPES);
    conv_frag_kernel<<<gwk, 256, 0, stream>>>(Wk, wkh, wkl, D, D,
                                              (size_t)D * D, (size_t)D * D);
    dim3 gw1(((FFDIM / 16) * 4 * 64 + 255) / 256, 1);
    conv_frag_kernel<<<gw1, 256, 0, stream>>>(W1, w1h, w1l, D, FFDIM, 0, 0);
    dim3 gw2((8 * (FFDIM / 32) * 64 + 255) / 256, 1);
    conv_frag_kernel<<<gw2, 256, 0, stream>>>(W2, w2h, w2l, FFDIM, D, 0, 0);
  }

  // K2: projections P[t] = bf16(z @ Wk[t] + bk[t]) via MFMA
  proj_mfma_kernel<<<(n + 63) / 64, 256, 0, stream>>>(zh, zl, wkh, wkl, bk, P, n);

  // K3: CSR build by src
  zero_kernel<<<(n + 255) / 256, 256, 0, stream>>>(cnt, n);
  hist_kernel<<<(E + 255) / 256, 256, 0, stream>>>(edges, cnt, E);
  scan_kernel<<<1, 1024, 0, stream>>>(cnt, offs, cursor, n);
  fill_kernel<<<(E + 255) / 256, 256, 0, stream>>>(edges, masks, flag, cursor, elist, E);

  // K4: attention -> out = x + attn
  attn_kernel<<<(n + 3) / 4, 256, 0, stream>>>(x, P, offs, elist, out, n);

  // K5: LN2 + FFN + residual via MFMA, in place on out
  ffn_mfma_kernel<<<(n + 63) / 64, 256, 0, stream>>>(w1h, w1l, w2h, w2l,
                                                     b1, b2, ln2_g, ln2_b, out, n);
}

// Round 4
// 426.005 us; speedup vs baseline: 1.8477x; 1.3084x over previous
//
#include <hip/hip_runtime.h>

// Problem constants (match reference)
#define D 128
#define H 8
#define DK 16
#define FFDIM 512
#define NTYPES 5
#define LN_EPS 1e-5f

typedef __bf16 bf16x8 __attribute__((ext_vector_type(8)));
typedef float f32x4 __attribute__((ext_vector_type(4)));
typedef unsigned short ushort_t;
typedef unsigned int uint_t;

__device__ inline ushort_t bfbits(float f) {
  __bf16 b = (__bf16)f;
  return __builtin_bit_cast(ushort_t, b);
}
__device__ inline float bf2f(ushort_t u) {
  return __uint_as_float(((uint_t)u) << 16);
}

// ---------------------------------------------------------------------------
// K0: detect mask dtype (byte-bool vs int32). flag=1 for byte masks.
// ---------------------------------------------------------------------------
__global__ void detect_kernel(const unsigned char* __restrict__ m8, int E,
                              int* __restrict__ flag) {
  if (threadIdx.x == 0 && blockIdx.x == 0) {
    int ok = 1;
    int lim = E < 64 ? E : 64;
    for (int e = 0; e < lim; ++e) {
      int s = 0;
      for (int i = 0; i < NTYPES; ++i) s += (m8[(size_t)i * E + e] != 0);
      if (s != 1) ok = 0;
    }
    *flag = ok;
  }
}

__device__ inline int decode_etype(const unsigned char* __restrict__ m8,
                                   int E, int e, int is8) {
  int t = 0;
  if (is8) {
#pragma unroll
    for (int i = 1; i < NTYPES; ++i) t += i * (m8[(size_t)i * E + e] != 0);
  } else {
    const int* m32 = (const int*)m8;
#pragma unroll
    for (int i = 1; i < NTYPES; ++i) t += i * (m32[(size_t)i * E + e] != 0);
  }
  return t > (NTYPES - 1) ? (NTYPES - 1) : t;
}

// ---------------------------------------------------------------------------
// K1: LayerNorm x -> z, stored as hi/lo bf16 split (parked in d_out)
// ---------------------------------------------------------------------------
__global__ __launch_bounds__(256) void ln1_kernel(
    const float* __restrict__ x, const float* __restrict__ g,
    const float* __restrict__ b, ushort_t* __restrict__ zh,
    ushort_t* __restrict__ zl, int n) {
  int row = blockIdx.x * 4 + (threadIdx.x >> 6);
  int lane = threadIdx.x & 63;
  if (row >= n) return;
  const float* xr = x + (size_t)row * D;
  float v0 = xr[lane], v1 = xr[lane + 64];
  float s = v0 + v1, ss = v0 * v0 + v1 * v1;
  for (int o = 32; o; o >>= 1) { s += __shfl_xor(s, o); ss += __shfl_xor(ss, o); }
  float mu = s * (1.f / D);
  float var = ss * (1.f / D) - mu * mu;
  float rs = rsqrtf(var + LN_EPS);
  float z0 = (v0 - mu) * rs * g[lane] + b[lane];
  float z1 = (v1 - mu) * rs * g[lane + 64] + b[lane + 64];
  size_t o0 = (size_t)row * D + lane, o1 = o0 + 64;
  __bf16 h0 = (__bf16)z0, h1 = (__bf16)z1;
  zh[o0] = __builtin_bit_cast(ushort_t, h0);
  zh[o1] = __builtin_bit_cast(ushort_t, h1);
  __bf16 l0 = (__bf16)(z0 - (float)h0), l1 = (__bf16)(z1 - (float)h1);
  zl[o0] = __builtin_bit_cast(ushort_t, l0);
  zl[o1] = __builtin_bit_cast(ushort_t, l1);
}

// ---------------------------------------------------------------------------
// K1b: convert a row-major f32 weight [K][N] into MFMA B-fragment order,
// hi/lo bf16 split.  frag[((c*(K/32)+kk)*64 + lane)*8 + j] =
//   W[kk*32 + (lane>>4)*8 + j][c*16 + (lane&15)]
// ---------------------------------------------------------------------------
__global__ void conv_frag_kernel(const float* __restrict__ W,
                                 ushort_t* __restrict__ hi,
                                 ushort_t* __restrict__ lo,
                                 int K, int Ncol, size_t matW, size_t matF) {
  int gid = blockIdx.x * 256 + threadIdx.x;
  int total = (Ncol / 16) * (K / 32) * 64;
  if (gid >= total) return;
  const float* Wm = W + (size_t)blockIdx.y * matW;
  ushort_t* him = hi + (size_t)blockIdx.y * matF;
  ushort_t* lom = lo + (size_t)blockIdx.y * matF;
  int l = gid & 63;
  int ck = gid >> 6;
  int kk = ck % (K / 32);
  int c = ck / (K / 32);
  int row0 = kk * 32 + (l >> 4) * 8;
  int col = c * 16 + (l & 15);
  size_t ob = (size_t)gid * 8;
#pragma unroll
  for (int j = 0; j < 8; ++j) {
    float w = Wm[(size_t)(row0 + j) * Ncol + col];
    __bf16 h = (__bf16)w;
    him[ob + j] = __builtin_bit_cast(ushort_t, h);
    __bf16 lo_ = (__bf16)(w - (float)h);
    lom[ob + j] = __builtin_bit_cast(ushort_t, lo_);
  }
}

// ---------------------------------------------------------------------------
// K2: proj via MFMA: P[t][node][d] = bf16( z @ Wk[t] + bk[t] )
// 4 waves/block, wave owns 16 rows. Batched B loads, split accumulators.
// ---------------------------------------------------------------------------
__global__ __launch_bounds__(256, 3) void proj_mfma_kernel(
    const ushort_t* __restrict__ zh, const ushort_t* __restrict__ zl,
    const ushort_t* __restrict__ wkh, const ushort_t* __restrict__ wkl,
    const float* __restrict__ bk, ushort_t* __restrict__ P, int n) {
  int w = threadIdx.x >> 6, l = threadIdx.x & 63;
  int n0 = blockIdx.x * 64 + w * 16;
  int arow = n0 + (l & 15);
  if (arow >= n) arow = n - 1;
  int koff = (l >> 4) * 8;
  bf16x8 ah[4], al[4];
#pragma unroll
  for (int kk = 0; kk < 4; ++kk) {
    size_t zo = (size_t)arow * D + kk * 32 + koff;
    ah[kk] = *(const bf16x8*)(zh + zo);
    al[kk] = *(const bf16x8*)(zl + zo);
  }
  int col16 = l & 15, rgrp = (l >> 4) * 4;
  for (int t = 0; t < NTYPES; ++t) {
    const ushort_t* bh0 = wkh + (size_t)t * (D * D);
    const ushort_t* bl0 = wkl + (size_t)t * (D * D);
    ushort_t* Pt = P + (size_t)t * n * D;
#pragma unroll
    for (int cp = 0; cp < 4; ++cp) {
      // batched B loads for the 2 c-tiles of this pair (16 x dwordx4)
      bf16x8 Bh[2][4], Bl[2][4];
#pragma unroll
      for (int cc = 0; cc < 2; ++cc)
#pragma unroll
        for (int kk = 0; kk < 4; ++kk) {
          size_t o = ((size_t)((cp * 2 + cc) * 4 + kk) * 64 + l) * 8;
          Bh[cc][kk] = *(const bf16x8*)(bh0 + o);
          Bl[cc][kk] = *(const bf16x8*)(bl0 + o);
        }
      // 6 independent accumulator chains of length 4
      f32x4 aa[2], ab[2], ac[2];
#pragma unroll
      for (int cc = 0; cc < 2; ++cc) {
        float bias = bk[t * D + (cp * 2 + cc) * 16 + col16];
        aa[cc] = (f32x4){bias, bias, bias, bias};
        ab[cc] = (f32x4){0.f, 0.f, 0.f, 0.f};
        ac[cc] = (f32x4){0.f, 0.f, 0.f, 0.f};
      }
#pragma unroll
      for (int kk = 0; kk < 4; ++kk)
#pragma unroll
        for (int cc = 0; cc < 2; ++cc) {
          aa[cc] = __builtin_amdgcn_mfma_f32_16x16x32_bf16(ah[kk], Bh[cc][kk], aa[cc], 0, 0, 0);
          ab[cc] = __builtin_amdgcn_mfma_f32_16x16x32_bf16(ah[kk], Bl[cc][kk], ab[cc], 0, 0, 0);
          ac[cc] = __builtin_amdgcn_mfma_f32_16x16x32_bf16(al[kk], Bh[cc][kk], ac[cc], 0, 0, 0);
        }
#pragma unroll
      for (int cc = 0; cc < 2; ++cc)
#pragma unroll
        for (int r = 0; r < 4; ++r) {
          int row = n0 + rgrp + r;
          if (row < n)
            Pt[(size_t)row * D + (cp * 2 + cc) * 16 + col16] =
                bfbits(aa[cc][r] + ab[cc][r] + ac[cc][r]);
        }
    }
  }
}

// ---------------------------------------------------------------------------
// K3: CSR build by src
// ---------------------------------------------------------------------------
__global__ void zero_kernel(int* __restrict__ p, int n) {
  int i = blockIdx.x * 256 + threadIdx.x;
  if (i < n) p[i] = 0;
}

__global__ void hist_kernel(const int* __restrict__ edges,
                            int* __restrict__ cnt, int E) {
  int e = blockIdx.x * 256 + threadIdx.x;
  if (e >= E) return;
  atomicAdd(&cnt[edges[e]], 1);
}

__global__ __launch_bounds__(1024) void scan_kernel(const int* __restrict__ cnt,
                                                    int* __restrict__ offs,
                                                    int* __restrict__ cursor,
                                                    int n) {
  __shared__ int sums[1024];
  int tid = threadIdx.x;
  int per = (n + 1023) / 1024;
  int start = tid * per;
  int end = min(start + per, n);
  int s = 0;
  for (int i = start; i < end; ++i) s += cnt[i];
  sums[tid] = s;
  __syncthreads();
  for (int o = 1; o < 1024; o <<= 1) {
    int v = (tid >= o) ? sums[tid - o] : 0;
    __syncthreads();
    sums[tid] += v;
    __syncthreads();
  }
  int base = sums[tid] - s;
  for (int i = start; i < end; ++i) {
    offs[i] = base;
    cursor[i] = base;
    base += cnt[i];
  }
  if (tid == 1023) offs[n] = sums[1023];
}

__global__ void fill_kernel(const int* __restrict__ edges,
                            const unsigned char* __restrict__ masks,
                            const int* __restrict__ flag,
                            int* __restrict__ cursor,
                            uint_t* __restrict__ elist, int E) {
  int e = blockIdx.x * 256 + threadIdx.x;
  if (e >= E) return;
  int is8 = *flag;
  int t = decode_etype(masks, E, e, is8);
  int dst = edges[E + e];
  int pos = atomicAdd(&cursor[edges[e]], 1);
  elist[pos] = ((uint_t)t << 29) | (uint_t)(dst & 0x1FFFFFFF);
}

// ---------------------------------------------------------------------------
// K4: per-node attention. 16 lanes per node (8 dims/lane), 4 nodes/wave.
// 16B vectorized k-gathers, prefetch depth 1. Head = lane pair (shfl_xor 1).
// writes x2 = x + attn into out (overwrites parked z).
// ---------------------------------------------------------------------------
__global__ __launch_bounds__(256) void attn_kernel(
    const float* __restrict__ x, const ushort_t* __restrict__ P,
    const int* __restrict__ offs, const uint_t* __restrict__ elist,
    float* __restrict__ out, int n) {
  int node = (blockIdx.x * 256 + threadIdx.x) >> 4;
  int gl = threadIdx.x & 15;
  if (node >= n) return;

  // q rows for all 5 types, kept as bf16x8 (static-index select later)
  bf16x8 qv0 = *(const bf16x8*)(P + ((size_t)0 * n + node) * D + gl * 8);
  bf16x8 qv1 = *(const bf16x8*)(P + ((size_t)1 * n + node) * D + gl * 8);
  bf16x8 qv2 = *(const bf16x8*)(P + ((size_t)2 * n + node) * D + gl * 8);
  bf16x8 qv3 = *(const bf16x8*)(P + ((size_t)3 * n + node) * D + gl * 8);
  bf16x8 qv4 = *(const bf16x8*)(P + ((size_t)4 * n + node) * D + gl * 8);

  float m = -1e30f, den = 0.f;
  float a[8];
#pragma unroll
  for (int i = 0; i < 8; ++i) a[i] = 0.f;

  int beg = offs[node], end = offs[node + 1];
  uint_t pv = 0;
  bf16x8 kv = {};
  if (beg < end) {
    pv = elist[beg];
    kv = *(const bf16x8*)(P + ((size_t)(pv >> 29) * n + (pv & 0x1FFFFFFF)) * D + gl * 8);
  }
  for (int j = beg; j < end; ++j) {
    uint_t pv_n = 0;
    bf16x8 kv_n = {};
    if (j + 1 < end) {
      pv_n = elist[j + 1];
      kv_n = *(const bf16x8*)(P + ((size_t)(pv_n >> 29) * n + (pv_n & 0x1FFFFFFF)) * D + gl * 8);
    }
    int t = pv >> 29;
    bf16x8 q = (t == 0) ? qv0 : (t == 1) ? qv1 : (t == 2) ? qv2 : (t == 3) ? qv3 : qv4;
    float kf[8], p = 0.f;
#pragma unroll
    for (int i = 0; i < 8; ++i) {
      kf[i] = (float)kv[i];
      p += (float)q[i] * kf[i];
    }
    p += __shfl_xor(p, 1);  // 16 dims/head = 2 lanes
    float newm = fmaxf(m, p);
    float scale = __expf(m - newm);
    float wgt = __expf(p - newm);
    den = den * scale + wgt;
#pragma unroll
    for (int i = 0; i < 8; ++i) a[i] = a[i] * scale + wgt * kf[i];
    m = newm;
    pv = pv_n;
    kv = kv_n;
  }
  float inv = (end > beg) ? 1.f / den : 0.f;
  const float* xr = x + (size_t)node * D + gl * 8;
  float* orow = out + (size_t)node * D + gl * 8;
  float4 xa = *(const float4*)xr;
  float4 xb = *(const float4*)(xr + 4);
  float4 oa, ob;
  oa.x = xa.x + a[0] * inv; oa.y = xa.y + a[1] * inv;
  oa.z = xa.z + a[2] * inv; oa.w = xa.w + a[3] * inv;
  ob.x = xb.x + a[4] * inv; ob.y = xb.y + a[5] * inv;
  ob.z = xb.z + a[6] * inv; ob.w = xb.w + a[7] * inv;
  *(float4*)orow = oa;
  *(float4*)(orow + 4) = ob;
}

// ---------------------------------------------------------------------------
// K5: fused LN2 + FFN + residual via MFMA, in-place on out (holds x2).
// 64 rows/block, 4 waves. Batched B loads, split accumulators, pad-36 bounce.
// ---------------------------------------------------------------------------
__global__ __launch_bounds__(256, 2) void ffn_mfma_kernel(
    const ushort_t* __restrict__ w1h, const ushort_t* __restrict__ w1l,
    const ushort_t* __restrict__ w2h, const ushort_t* __restrict__ w2l,
    const float* __restrict__ b1, const float* __restrict__ b2,
    const float* __restrict__ g, const float* __restrict__ bln,
    float* __restrict__ out, int n) {
  __shared__ ushort_t z2h[64 * D];
  __shared__ ushort_t z2l[64 * D];
  __shared__ float hmb[4][16 * 36];  // per-wave bounce, pad 36 (2-way = free)
  int tid = threadIdx.x, w = tid >> 6, l = tid & 63;
  int n0 = blockIdx.x * 64;

  // Phase 0: LN2, write z2 hi/lo into XOR-swizzled LDS
  for (int i = w; i < 64; i += 4) {
    int r = n0 + i;
    float v0 = 0.f, v1 = 0.f;
    if (r < n) {
      v0 = out[(size_t)r * D + l];
      v1 = out[(size_t)r * D + 64 + l];
    }
    float s = v0 + v1, ss = v0 * v0 + v1 * v1;
    for (int o = 32; o; o >>= 1) { s += __shfl_xor(s, o); ss += __shfl_xor(ss, o); }
    float mu = s * (1.f / D);
    float var = ss * (1.f / D) - mu * mu;
    float rs = rsqrtf(var + LN_EPS);
    float z0 = (v0 - mu) * rs * g[l] + bln[l];
    float z1 = (v1 - mu) * rs * g[l + 64] + bln[l + 64];
    int sw = (i & 7) << 3;
    int e0 = (i * D + l) ^ sw;
    int e1 = (i * D + l + 64) ^ sw;
    __bf16 h0 = (__bf16)z0, h1 = (__bf16)z1;
    z2h[e0] = __builtin_bit_cast(ushort_t, h0);
    z2h[e1] = __builtin_bit_cast(ushort_t, h1);
    __bf16 l0 = (__bf16)(z0 - (float)h0), l1 = (__bf16)(z1 - (float)h1);
    z2l[e0] = __builtin_bit_cast(ushort_t, l0);
    z2l[e1] = __builtin_bit_cast(ushort_t, l1);
  }
  __syncthreads();

  // A-fragments of z2 for this wave (16 rows)
  int lrow = w * 16 + (l & 15);
  int koff = (l >> 4) * 8;
  bf16x8 ah[4], al[4];
#pragma unroll
  for (int kk = 0; kk < 4; ++kk) {
    int e = (lrow * D + kk * 32 + koff) ^ ((lrow & 7) << 3);
    ah[kk] = *(const bf16x8*)(z2h + e);
    al[kk] = *(const bf16x8*)(z2l + e);
  }

  int col16 = l & 15, rgrp = (l >> 4) * 4;
  f32x4 acc2[8];
#pragma unroll
  for (int c = 0; c < 8; ++c) acc2[c] = (f32x4){0.f, 0.f, 0.f, 0.f};
  float* hbp = &hmb[w][0];

  for (int kk2 = 0; kk2 < 16; ++kk2) {
    // ---- batched W1 fragment loads (16 x dwordx4, all in flight)
    bf16x8 B1h[2][4], B1l[2][4];
#pragma unroll
    for (int cc = 0; cc < 2; ++cc)
#pragma unroll
      for (int kk = 0; kk < 4; ++kk) {
        size_t o = ((size_t)((kk2 * 2 + cc) * 4 + kk) * 64 + l) * 8;
        B1h[cc][kk] = *(const bf16x8*)(w1h + o);
        B1l[cc][kk] = *(const bf16x8*)(w1l + o);
      }
    // ---- Hm chunk: 6 independent chains of length 4
    f32x4 ha[2], hb[2], hc[2];
#pragma unroll
    for (int cc = 0; cc < 2; ++cc) {
      float bias = b1[(kk2 * 2 + cc) * 16 + col16];
      ha[cc] = (f32x4){bias, bias, bias, bias};
      hb[cc] = (f32x4){0.f, 0.f, 0.f, 0.f};
      hc[cc] = (f32x4){0.f, 0.f, 0.f, 0.f};
    }
#pragma unroll
    for (int kk = 0; kk < 4; ++kk)
#pragma unroll
      for (int cc = 0; cc < 2; ++cc) {
        ha[cc] = __builtin_amdgcn_mfma_f32_16x16x32_bf16(ah[kk], B1h[cc][kk], ha[cc], 0, 0, 0);
        hb[cc] = __builtin_amdgcn_mfma_f32_16x16x32_bf16(ah[kk], B1l[cc][kk], hb[cc], 0, 0, 0);
        hc[cc] = __builtin_amdgcn_mfma_f32_16x16x32_bf16(al[kk], B1h[cc][kk], hc[cc], 0, 0, 0);
      }
    // ---- bounce through padded per-wave LDS tile (relu fused)
#pragma unroll
    for (int cc = 0; cc < 2; ++cc)
#pragma unroll
      for (int r = 0; r < 4; ++r)
        hbp[(rgrp + r) * 36 + cc * 16 + col16] =
            fmaxf(ha[cc][r] + hb[cc][r] + hc[cc][r], 0.f);
    // ---- re-fragment (lane -> row=l&15, k=koff..koff+7), hi/lo split
    float av[8];
    *(float4*)&av[0] = *(const float4*)&hbp[(l & 15) * 36 + koff];
    *(float4*)&av[4] = *(const float4*)&hbp[(l & 15) * 36 + koff + 4];
    bf16x8 a2h, a2l;
#pragma unroll
    for (int j = 0; j < 8; ++j) {
      __bf16 hv = (__bf16)av[j];
      a2h[j] = hv;
      a2l[j] = (__bf16)(av[j] - (float)hv);
    }
    // ---- batched W2 fragment loads (16 x dwordx4)
    bf16x8 B2h[8], B2l[8];
#pragma unroll
    for (int c2 = 0; c2 < 8; ++c2) {
      size_t o = ((size_t)(c2 * 16 + kk2) * 64 + l) * 8;
      B2h[c2] = *(const bf16x8*)(w2h + o);
      B2l[c2] = *(const bf16x8*)(w2l + o);
    }
    // ---- second GEMM: 8 independent chains of 3
#pragma unroll
    for (int c2 = 0; c2 < 8; ++c2) {
      acc2[c2] = __builtin_amdgcn_mfma_f32_16x16x32_bf16(a2h, B2h[c2], acc2[c2], 0, 0, 0);
      acc2[c2] = __builtin_amdgcn_mfma_f32_16x16x32_bf16(a2h, B2l[c2], acc2[c2], 0, 0, 0);
      acc2[c2] = __builtin_amdgcn_mfma_f32_16x16x32_bf16(a2l, B2h[c2], acc2[c2], 0, 0, 0);
    }
  }

  // Epilogue: out += ff + b2
#pragma unroll
  for (int c2 = 0; c2 < 8; ++c2) {
    float bias2 = b2[c2 * 16 + col16];
#pragma unroll
    for (int r = 0; r < 4; ++r) {
      int row = n0 + w * 16 + rgrp + r;
      if (row < n) {
        size_t o = (size_t)row * D + c2 * 16 + col16;
        out[o] = out[o] + acc2[c2][r] + bias2;
      }
    }
  }
}

// ---------------------------------------------------------------------------
extern "C" void kernel_launch(void* const* d_in, const int* in_sizes, int n_in,
                              void* d_out, int out_size, void* d_ws, size_t ws_size,
                              hipStream_t stream) {
  const float* x      = (const float*)d_in[0];
  const int* edges    = (const int*)d_in[1];
  const unsigned char* masks = (const unsigned char*)d_in[2];
  const float* Wk     = (const float*)d_in[3];
  const float* bk     = (const float*)d_in[4];
  const float* ln1_g  = (const float*)d_in[5];
  const float* ln1_b  = (const float*)d_in[6];
  const float* ln2_g  = (const float*)d_in[7];
  const float* ln2_b  = (const float*)d_in[8];
  const float* W1     = (const float*)d_in[9];
  const float* b1     = (const float*)d_in[10];
  const float* W2     = (const float*)d_in[11];
  const float* b2     = (const float*)d_in[12];
  float* out = (float*)d_out;

  const int n = in_sizes[0] / D;
  const int E = in_sizes[1] / 2;

  // workspace layout (~68.7 MB)
  char* ws = (char*)d_ws;
  size_t off = 0;
  ushort_t* P = (ushort_t*)(ws + off);  off += (size_t)NTYPES * n * D * sizeof(ushort_t);
  int* cnt    = (int*)(ws + off);       off += (size_t)n * sizeof(int);
  int* offs   = (int*)(ws + off);       off += (size_t)(n + 1) * sizeof(int);
  int* cursor = (int*)(ws + off);       off += (size_t)n * sizeof(int);
  uint_t* elist = (uint_t*)(ws + off);  off += (size_t)E * sizeof(uint_t);
  int* flag   = (int*)(ws + off);       off += 64;
  ushort_t* wkh = (ushort_t*)(ws + off); off += (size_t)NTYPES * D * D * sizeof(ushort_t);
  ushort_t* wkl = (ushort_t*)(ws + off); off += (size_t)NTYPES * D * D * sizeof(ushort_t);
  ushort_t* w1h = (ushort_t*)(ws + off); off += (size_t)D * FFDIM * sizeof(ushort_t);
  ushort_t* w1l = (ushort_t*)(ws + off); off += (size_t)D * FFDIM * sizeof(ushort_t);
  ushort_t* w2h = (ushort_t*)(ws + off); off += (size_t)FFDIM * D * sizeof(ushort_t);
  ushort_t* w2l = (ushort_t*)(ws + off); off += (size_t)FFDIM * D * sizeof(ushort_t);
  (void)ws_size; (void)n_in; (void)out_size;

  // z hi/lo parked in d_out (dead before attn writes x2 there)
  ushort_t* zh = (ushort_t*)out;
  ushort_t* zl = zh + (size_t)n * D;

  // K0: mask dtype detection
  detect_kernel<<<1, 64, 0, stream>>>(masks, E, flag);

  // K1: LN1 -> z hi/lo
  ln1_kernel<<<(n + 3) / 4, 256, 0, stream>>>(x, ln1_g, ln1_b, zh, zl, n);

  // K1b: weight fragment conversion
  {
    dim3 gwk((8 * 4 * 64 + 255) / 256, NTYPES);
    conv_frag_kernel<<<gwk, 256, 0, stream>>>(Wk, wkh, wkl, D, D,
                                              (size_t)D * D, (size_t)D * D);
    dim3 gw1(((FFDIM / 16) * 4 * 64 + 255) / 256, 1);
    conv_frag_kernel<<<gw1, 256, 0, stream>>>(W1, w1h, w1l, D, FFDIM, 0, 0);
    dim3 gw2((8 * (FFDIM / 32) * 64 + 255) / 256, 1);
    conv_frag_kernel<<<gw2, 256, 0, stream>>>(W2, w2h, w2l, FFDIM, D, 0, 0);
  }

  // K2: projections P[t] = bf16(z @ Wk[t] + bk[t]) via MFMA
  proj_mfma_kernel<<<(n + 63) / 64, 256, 0, stream>>>(zh, zl, wkh, wkl, bk, P, n);

  // K3: CSR build by src
  zero_kernel<<<(n + 255) / 256, 256, 0, stream>>>(cnt, n);
  hist_kernel<<<(E + 255) / 256, 256, 0, stream>>>(edges, cnt, E);
  scan_kernel<<<1, 1024, 0, stream>>>(cnt, offs, cursor, n);
  fill_kernel<<<(E + 255) / 256, 256, 0, stream>>>(edges, masks, flag, cursor, elist, E);

  // K4: attention -> out = x + attn  (16 nodes per 256-thread block)
  attn_kernel<<<(n + 15) / 16, 256, 0, stream>>>(x, P, offs, elist, out, n);

  // K5: LN2 + FFN + residual via MFMA, in place on out
  ffn_mfma_kernel<<<(n + 63) / 64, 256, 0, stream>>>(w1h, w1l, w2h, w2l,
                                                     b1, b2, ln2_g, ln2_b, out, n);
}

// Round 5
// 328.471 us; speedup vs baseline: 2.3964x; 1.2969x over previous
//
#include <hip/hip_runtime.h>

// Problem constants (match reference)
#define D 128
#define H 8
#define DK 16
#define FFDIM 512
#define NTYPES 5
#define LN_EPS 1e-5f

typedef __bf16 bf16x8 __attribute__((ext_vector_type(8)));
typedef float f32x4 __attribute__((ext_vector_type(4)));
typedef unsigned short ushort_t;
typedef unsigned int uint_t;

__device__ inline ushort_t bfbits(float f) {
  __bf16 b = (__bf16)f;
  return __builtin_bit_cast(ushort_t, b);
}
__device__ inline float bf2f(ushort_t u) {
  return __uint_as_float(((uint_t)u) << 16);
}

// ---------------------------------------------------------------------------
// K0: detect mask dtype (byte-bool vs int32). flag=1 for byte masks.
// ---------------------------------------------------------------------------
__global__ void detect_kernel(const unsigned char* __restrict__ m8, int E,
                              int* __restrict__ flag) {
  if (threadIdx.x == 0 && blockIdx.x == 0) {
    int ok = 1;
    int lim = E < 64 ? E : 64;
    for (int e = 0; e < lim; ++e) {
      int s = 0;
      for (int i = 0; i < NTYPES; ++i) s += (m8[(size_t)i * E + e] != 0);
      if (s != 1) ok = 0;
    }
    *flag = ok;
  }
}

__device__ inline int decode_etype(const unsigned char* __restrict__ m8,
                                   int E, int e, int is8) {
  int t = 0;
  if (is8) {
#pragma unroll
    for (int i = 1; i < NTYPES; ++i) t += i * (m8[(size_t)i * E + e] != 0);
  } else {
    const int* m32 = (const int*)m8;
#pragma unroll
    for (int i = 1; i < NTYPES; ++i) t += i * (m32[(size_t)i * E + e] != 0);
  }
  return t > (NTYPES - 1) ? (NTYPES - 1) : t;
}

// ---------------------------------------------------------------------------
// K1: LayerNorm x -> z, stored as hi/lo bf16 split (parked in d_out)
// ---------------------------------------------------------------------------
__global__ __launch_bounds__(256) void ln1_kernel(
    const float* __restrict__ x, const float* __restrict__ g,
    const float* __restrict__ b, ushort_t* __restrict__ zh,
    ushort_t* __restrict__ zl, int n) {
  int row = blockIdx.x * 4 + (threadIdx.x >> 6);
  int lane = threadIdx.x & 63;
  if (row >= n) return;
  const float* xr = x + (size_t)row * D;
  float v0 = xr[lane], v1 = xr[lane + 64];
  float s = v0 + v1, ss = v0 * v0 + v1 * v1;
  for (int o = 32; o; o >>= 1) { s += __shfl_xor(s, o); ss += __shfl_xor(ss, o); }
  float mu = s * (1.f / D);
  float var = ss * (1.f / D) - mu * mu;
  float rs = rsqrtf(var + LN_EPS);
  float z0 = (v0 - mu) * rs * g[lane] + b[lane];
  float z1 = (v1 - mu) * rs * g[lane + 64] + b[lane + 64];
  size_t o0 = (size_t)row * D + lane, o1 = o0 + 64;
  __bf16 h0 = (__bf16)z0, h1 = (__bf16)z1;
  zh[o0] = __builtin_bit_cast(ushort_t, h0);
  zh[o1] = __builtin_bit_cast(ushort_t, h1);
  __bf16 l0 = (__bf16)(z0 - (float)h0), l1 = (__bf16)(z1 - (float)h1);
  zl[o0] = __builtin_bit_cast(ushort_t, l0);
  zl[o1] = __builtin_bit_cast(ushort_t, l1);
}

// ---------------------------------------------------------------------------
// K1b: convert a row-major f32 weight [K][N] into MFMA B-fragment order,
// hi/lo bf16 split.
// ---------------------------------------------------------------------------
__global__ void conv_frag_kernel(const float* __restrict__ W,
                                 ushort_t* __restrict__ hi,
                                 ushort_t* __restrict__ lo,
                                 int K, int Ncol, size_t matW, size_t matF) {
  int gid = blockIdx.x * 256 + threadIdx.x;
  int total = (Ncol / 16) * (K / 32) * 64;
  if (gid >= total) return;
  const float* Wm = W + (size_t)blockIdx.y * matW;
  ushort_t* him = hi + (size_t)blockIdx.y * matF;
  ushort_t* lom = lo + (size_t)blockIdx.y * matF;
  int l = gid & 63;
  int ck = gid >> 6;
  int kk = ck % (K / 32);
  int c = ck / (K / 32);
  int row0 = kk * 32 + (l >> 4) * 8;
  int col = c * 16 + (l & 15);
  size_t ob = (size_t)gid * 8;
#pragma unroll
  for (int j = 0; j < 8; ++j) {
    float w = Wm[(size_t)(row0 + j) * Ncol + col];
    __bf16 h = (__bf16)w;
    him[ob + j] = __builtin_bit_cast(ushort_t, h);
    __bf16 lo_ = (__bf16)(w - (float)h);
    lom[ob + j] = __builtin_bit_cast(ushort_t, lo_);
  }
}

// ---------------------------------------------------------------------------
// K2: proj via MFMA: P[t][node][d] = bf16( z @ Wk[t] + bk[t] )
// ---------------------------------------------------------------------------
__global__ __launch_bounds__(256, 3) void proj_mfma_kernel(
    const ushort_t* __restrict__ zh, const ushort_t* __restrict__ zl,
    const ushort_t* __restrict__ wkh, const ushort_t* __restrict__ wkl,
    const float* __restrict__ bk, ushort_t* __restrict__ P, int n) {
  int w = threadIdx.x >> 6, l = threadIdx.x & 63;
  int n0 = blockIdx.x * 64 + w * 16;
  int arow = n0 + (l & 15);
  if (arow >= n) arow = n - 1;
  int koff = (l >> 4) * 8;
  bf16x8 ah[4], al[4];
#pragma unroll
  for (int kk = 0; kk < 4; ++kk) {
    size_t zo = (size_t)arow * D + kk * 32 + koff;
    ah[kk] = *(const bf16x8*)(zh + zo);
    al[kk] = *(const bf16x8*)(zl + zo);
  }
  int col16 = l & 15, rgrp = (l >> 4) * 4;
  for (int t = 0; t < NTYPES; ++t) {
    const ushort_t* bh0 = wkh + (size_t)t * (D * D);
    const ushort_t* bl0 = wkl + (size_t)t * (D * D);
    ushort_t* Pt = P + (size_t)t * n * D;
#pragma unroll
    for (int cp = 0; cp < 4; ++cp) {
      bf16x8 Bh[2][4], Bl[2][4];
#pragma unroll
      for (int cc = 0; cc < 2; ++cc)
#pragma unroll
        for (int kk = 0; kk < 4; ++kk) {
          size_t o = ((size_t)((cp * 2 + cc) * 4 + kk) * 64 + l) * 8;
          Bh[cc][kk] = *(const bf16x8*)(bh0 + o);
          Bl[cc][kk] = *(const bf16x8*)(bl0 + o);
        }
      f32x4 aa[2], ab[2], ac[2];
#pragma unroll
      for (int cc = 0; cc < 2; ++cc) {
        float bias = bk[t * D + (cp * 2 + cc) * 16 + col16];
        aa[cc] = (f32x4){bias, bias, bias, bias};
        ab[cc] = (f32x4){0.f, 0.f, 0.f, 0.f};
        ac[cc] = (f32x4){0.f, 0.f, 0.f, 0.f};
      }
#pragma unroll
      for (int kk = 0; kk < 4; ++kk)
#pragma unroll
        for (int cc = 0; cc < 2; ++cc) {
          aa[cc] = __builtin_amdgcn_mfma_f32_16x16x32_bf16(ah[kk], Bh[cc][kk], aa[cc], 0, 0, 0);
          ab[cc] = __builtin_amdgcn_mfma_f32_16x16x32_bf16(ah[kk], Bl[cc][kk], ab[cc], 0, 0, 0);
          ac[cc] = __builtin_amdgcn_mfma_f32_16x16x32_bf16(al[kk], Bh[cc][kk], ac[cc], 0, 0, 0);
        }
#pragma unroll
      for (int cc = 0; cc < 2; ++cc)
#pragma unroll
        for (int r = 0; r < 4; ++r) {
          int row = n0 + rgrp + r;
          if (row < n)
            Pt[(size_t)row * D + (cp * 2 + cc) * 16 + col16] =
                bfbits(aa[cc][r] + ab[cc][r] + ac[cc][r]);
        }
    }
  }
}

// ---------------------------------------------------------------------------
// K3: CSR build by src — hist + hierarchical 3-pass scan + fill
// ---------------------------------------------------------------------------
__global__ void zero_kernel(int* __restrict__ p, int n) {
  int i = blockIdx.x * 256 + threadIdx.x;
  if (i < n) p[i] = 0;
}

__global__ void hist_kernel(const int* __restrict__ edges,
                            int* __restrict__ cnt, int E) {
  int e = blockIdx.x * 256 + threadIdx.x;
  if (e >= E) return;
  atomicAdd(&cnt[edges[e]], 1);
}

// scanA: each block scans 1024 elements (4/thread); local exclusive -> loc,
// block total -> bsums[b]
__global__ __launch_bounds__(256) void scanA_kernel(const int* __restrict__ cnt,
                                                    int* __restrict__ loc,
                                                    int* __restrict__ bsums, int n) {
  __shared__ int ts[256];
  int tid = threadIdx.x;
  int base = blockIdx.x * 1024 + tid * 4;
  int v0 = (base + 0 < n) ? cnt[base + 0] : 0;
  int v1 = (base + 1 < n) ? cnt[base + 1] : 0;
  int v2 = (base + 2 < n) ? cnt[base + 2] : 0;
  int v3 = (base + 3 < n) ? cnt[base + 3] : 0;
  int s = v0 + v1 + v2 + v3;
  ts[tid] = s;
  __syncthreads();
  for (int o = 1; o < 256; o <<= 1) {
    int t = (tid >= o) ? ts[tid - o] : 0;
    __syncthreads();
    ts[tid] += t;
    __syncthreads();
  }
  int run = ts[tid] - s;
  if (base + 0 < n) loc[base + 0] = run;  run += v0;
  if (base + 1 < n) loc[base + 1] = run;  run += v1;
  if (base + 2 < n) loc[base + 2] = run;  run += v2;
  if (base + 3 < n) loc[base + 3] = run;
  if (tid == 255) bsums[blockIdx.x] = ts[255];
}

// scanB: single block, exclusive scan of nb block sums in place + total
__global__ __launch_bounds__(256) void scanB_kernel(int* __restrict__ bsums, int nb,
                                                    int* __restrict__ total) {
  __shared__ int ts[256];
  int tid = threadIdx.x;
  int per = (nb + 255) / 256;
  int start = tid * per;
  int end = min(start + per, nb);
  int s = 0;
  for (int i = start; i < end; ++i) s += bsums[i];
  ts[tid] = s;
  __syncthreads();
  for (int o = 1; o < 256; o <<= 1) {
    int t = (tid >= o) ? ts[tid - o] : 0;
    __syncthreads();
    ts[tid] += t;
    __syncthreads();
  }
  int run = ts[tid] - s;
  for (int i = start; i < end; ++i) {
    int v = bsums[i];
    bsums[i] = run;
    run += v;
  }
  if (tid == 255) *total = ts[255];
}

// scanC: offs[i] = loc[i] + bsums[i>>10]; cursor dup; offs[n] = total
__global__ void scanC_kernel(const int* __restrict__ loc,
                             const int* __restrict__ bsums,
                             const int* __restrict__ total,
                             int* __restrict__ offs, int* __restrict__ cursor,
                             int n) {
  int i = blockIdx.x * 256 + threadIdx.x;
  if (i < n) {
    int o = loc[i] + bsums[i >> 10];
    offs[i] = o;
    cursor[i] = o;
  }
  if (i == 0) offs[n] = *total;
}

__global__ void fill_kernel(const int* __restrict__ edges,
                            const unsigned char* __restrict__ masks,
                            const int* __restrict__ flag,
                            int* __restrict__ cursor,
                            uint_t* __restrict__ elist, int E) {
  int e = blockIdx.x * 256 + threadIdx.x;
  if (e >= E) return;
  int is8 = *flag;
  int t = decode_etype(masks, E, e, is8);
  int dst = edges[E + e];
  int pos = atomicAdd(&cursor[edges[e]], 1);
  elist[pos] = ((uint_t)t << 29) | (uint_t)(dst & 0x1FFFFFFF);
}

// ---------------------------------------------------------------------------
// K4: per-node attention. 16 lanes per node (8 dims/lane), 4 nodes/wave.
// ---------------------------------------------------------------------------
__global__ __launch_bounds__(256) void attn_kernel(
    const float* __restrict__ x, const ushort_t* __restrict__ P,
    const int* __restrict__ offs, const uint_t* __restrict__ elist,
    float* __restrict__ out, int n) {
  int node = (blockIdx.x * 256 + threadIdx.x) >> 4;
  int gl = threadIdx.x & 15;
  if (node >= n) return;

  bf16x8 qv0 = *(const bf16x8*)(P + ((size_t)0 * n + node) * D + gl * 8);
  bf16x8 qv1 = *(const bf16x8*)(P + ((size_t)1 * n + node) * D + gl * 8);
  bf16x8 qv2 = *(const bf16x8*)(P + ((size_t)2 * n + node) * D + gl * 8);
  bf16x8 qv3 = *(const bf16x8*)(P + ((size_t)3 * n + node) * D + gl * 8);
  bf16x8 qv4 = *(const bf16x8*)(P + ((size_t)4 * n + node) * D + gl * 8);

  float m = -1e30f, den = 0.f;
  float a[8];
#pragma unroll
  for (int i = 0; i < 8; ++i) a[i] = 0.f;

  int beg = offs[node], end = offs[node + 1];
  uint_t pv = 0;
  bf16x8 kv = {};
  if (beg < end) {
    pv = elist[beg];
    kv = *(const bf16x8*)(P + ((size_t)(pv >> 29) * n + (pv & 0x1FFFFFFF)) * D + gl * 8);
  }
  for (int j = beg; j < end; ++j) {
    uint_t pv_n = 0;
    bf16x8 kv_n = {};
    if (j + 1 < end) {
      pv_n = elist[j + 1];
      kv_n = *(const bf16x8*)(P + ((size_t)(pv_n >> 29) * n + (pv_n & 0x1FFFFFFF)) * D + gl * 8);
    }
    int t = pv >> 29;
    bf16x8 q = (t == 0) ? qv0 : (t == 1) ? qv1 : (t == 2) ? qv2 : (t == 3) ? qv3 : qv4;
    float kf[8], p = 0.f;
#pragma unroll
    for (int i = 0; i < 8; ++i) {
      kf[i] = (float)kv[i];
      p += (float)q[i] * kf[i];
    }
    p += __shfl_xor(p, 1);
    float newm = fmaxf(m, p);
    float scale = __expf(m - newm);
    float wgt = __expf(p - newm);
    den = den * scale + wgt;
#pragma unroll
    for (int i = 0; i < 8; ++i) a[i] = a[i] * scale + wgt * kf[i];
    m = newm;
    pv = pv_n;
    kv = kv_n;
  }
  float inv = (end > beg) ? 1.f / den : 0.f;
  const float* xr = x + (size_t)node * D + gl * 8;
  float* orow = out + (size_t)node * D + gl * 8;
  float4 xa = *(const float4*)xr;
  float4 xb = *(const float4*)(xr + 4);
  float4 oa, ob;
  oa.x = xa.x + a[0] * inv; oa.y = xa.y + a[1] * inv;
  oa.z = xa.z + a[2] * inv; oa.w = xa.w + a[3] * inv;
  ob.x = xb.x + a[4] * inv; ob.y = xb.y + a[5] * inv;
  ob.z = xb.z + a[6] * inv; ob.w = xb.w + a[7] * inv;
  *(float4*)orow = oa;
  *(float4*)(orow + 4) = ob;
}

// ---------------------------------------------------------------------------
// K5: fused LN2 + FFN + residual via MFMA, in-place on out (holds x2).
// ---------------------------------------------------------------------------
__global__ __launch_bounds__(256, 2) void ffn_mfma_kernel(
    const ushort_t* __restrict__ w1h, const ushort_t* __restrict__ w1l,
    const ushort_t* __restrict__ w2h, const ushort_t* __restrict__ w2l,
    const float* __restrict__ b1, const float* __restrict__ b2,
    const float* __restrict__ g, const float* __restrict__ bln,
    float* __restrict__ out, int n) {
  __shared__ ushort_t z2h[64 * D];
  __shared__ ushort_t z2l[64 * D];
  __shared__ float hmb[4][16 * 36];
  int tid = threadIdx.x, w = tid >> 6, l = tid & 63;
  int n0 = blockIdx.x * 64;

  for (int i = w; i < 64; i += 4) {
    int r = n0 + i;
    float v0 = 0.f, v1 = 0.f;
    if (r < n) {
      v0 = out[(size_t)r * D + l];
      v1 = out[(size_t)r * D + 64 + l];
    }
    float s = v0 + v1, ss = v0 * v0 + v1 * v1;
    for (int o = 32; o; o >>= 1) { s += __shfl_xor(s, o); ss += __shfl_xor(ss, o); }
    float mu = s * (1.f / D);
    float var = ss * (1.f / D) - mu * mu;
    float rs = rsqrtf(var + LN_EPS);
    float z0 = (v0 - mu) * rs * g[l] + bln[l];
    float z1 = (v1 - mu) * rs * g[l + 64] + bln[l + 64];
    int sw = (i & 7) << 3;
    int e0 = (i * D + l) ^ sw;
    int e1 = (i * D + l + 64) ^ sw;
    __bf16 h0 = (__bf16)z0, h1 = (__bf16)z1;
    z2h[e0] = __builtin_bit_cast(ushort_t, h0);
    z2h[e1] = __builtin_bit_cast(ushort_t, h1);
    __bf16 l0 = (__bf16)(z0 - (float)h0), l1 = (__bf16)(z1 - (float)h1);
    z2l[e0] = __builtin_bit_cast(ushort_t, l0);
    z2l[e1] = __builtin_bit_cast(ushort_t, l1);
  }
  __syncthreads();

  int lrow = w * 16 + (l & 15);
  int koff = (l >> 4) * 8;
  bf16x8 ah[4], al[4];
#pragma unroll
  for (int kk = 0; kk < 4; ++kk) {
    int e = (lrow * D + kk * 32 + koff) ^ ((lrow & 7) << 3);
    ah[kk] = *(const bf16x8*)(z2h + e);
    al[kk] = *(const bf16x8*)(z2l + e);
  }

  int col16 = l & 15, rgrp = (l >> 4) * 4;
  f32x4 acc2[8];
#pragma unroll
  for (int c = 0; c < 8; ++c) acc2[c] = (f32x4){0.f, 0.f, 0.f, 0.f};
  float* hbp = &hmb[w][0];

  for (int kk2 = 0; kk2 < 16; ++kk2) {
    bf16x8 B1h[2][4], B1l[2][4];
#pragma unroll
    for (int cc = 0; cc < 2; ++cc)
#pragma unroll
      for (int kk = 0; kk < 4; ++kk) {
        size_t o = ((size_t)((kk2 * 2 + cc) * 4 + kk) * 64 + l) * 8;
        B1h[cc][kk] = *(const bf16x8*)(w1h + o);
        B1l[cc][kk] = *(const bf16x8*)(w1l + o);
      }
    f32x4 ha[2], hb[2], hc[2];
#pragma unroll
    for (int cc = 0; cc < 2; ++cc) {
      float bias = b1[(kk2 * 2 + cc) * 16 + col16];
      ha[cc] = (f32x4){bias, bias, bias, bias};
      hb[cc] = (f32x4){0.f, 0.f, 0.f, 0.f};
      hc[cc] = (f32x4){0.f, 0.f, 0.f, 0.f};
    }
#pragma unroll
    for (int kk = 0; kk < 4; ++kk)
#pragma unroll
      for (int cc = 0; cc < 2; ++cc) {
        ha[cc] = __builtin_amdgcn_mfma_f32_16x16x32_bf16(ah[kk], B1h[cc][kk], ha[cc], 0, 0, 0);
        hb[cc] = __builtin_amdgcn_mfma_f32_16x16x32_bf16(ah[kk], B1l[cc][kk], hb[cc], 0, 0, 0);
        hc[cc] = __builtin_amdgcn_mfma_f32_16x16x32_bf16(al[kk], B1h[cc][kk], hc[cc], 0, 0, 0);
      }
#pragma unroll
    for (int cc = 0; cc < 2; ++cc)
#pragma unroll
      for (int r = 0; r < 4; ++r)
        hbp[(rgrp + r) * 36 + cc * 16 + col16] =
            fmaxf(ha[cc][r] + hb[cc][r] + hc[cc][r], 0.f);
    float av[8];
    *(float4*)&av[0] = *(const float4*)&hbp[(l & 15) * 36 + koff];
    *(float4*)&av[4] = *(const float4*)&hbp[(l & 15) * 36 + koff + 4];
    bf16x8 a2h, a2l;
#pragma unroll
    for (int j = 0; j < 8; ++j) {
      __bf16 hv = (__bf16)av[j];
      a2h[j] = hv;
      a2l[j] = (__bf16)(av[j] - (float)hv);
    }
    bf16x8 B2h[8], B2l[8];
#pragma unroll
    for (int c2 = 0; c2 < 8; ++c2) {
      size_t o = ((size_t)(c2 * 16 + kk2) * 64 + l) * 8;
      B2h[c2] = *(const bf16x8*)(w2h + o);
      B2l[c2] = *(const bf16x8*)(w2l + o);
    }
#pragma unroll
    for (int c2 = 0; c2 < 8; ++c2) {
      acc2[c2] = __builtin_amdgcn_mfma_f32_16x16x32_bf16(a2h, B2h[c2], acc2[c2], 0, 0, 0);
      acc2[c2] = __builtin_amdgcn_mfma_f32_16x16x32_bf16(a2h, B2l[c2], acc2[c2], 0, 0, 0);
      acc2[c2] = __builtin_amdgcn_mfma_f32_16x16x32_bf16(a2l, B2h[c2], acc2[c2], 0, 0, 0);
    }
  }

#pragma unroll
  for (int c2 = 0; c2 < 8; ++c2) {
    float bias2 = b2[c2 * 16 + col16];
#pragma unroll
    for (int r = 0; r < 4; ++r) {
      int row = n0 + w * 16 + rgrp + r;
      if (row < n) {
        size_t o = (size_t)row * D + c2 * 16 + col16;
        out[o] = out[o] + acc2[c2][r] + bias2;
      }
    }
  }
}

// ---------------------------------------------------------------------------
extern "C" void kernel_launch(void* const* d_in, const int* in_sizes, int n_in,
                              void* d_out, int out_size, void* d_ws, size_t ws_size,
                              hipStream_t stream) {
  const float* x      = (const float*)d_in[0];
  const int* edges    = (const int*)d_in[1];
  const unsigned char* masks = (const unsigned char*)d_in[2];
  const float* Wk     = (const float*)d_in[3];
  const float* bk     = (const float*)d_in[4];
  const float* ln1_g  = (const float*)d_in[5];
  const float* ln1_b  = (const float*)d_in[6];
  const float* ln2_g  = (const float*)d_in[7];
  const float* ln2_b  = (const float*)d_in[8];
  const float* W1     = (const float*)d_in[9];
  const float* b1     = (const float*)d_in[10];
  const float* W2     = (const float*)d_in[11];
  const float* b2     = (const float*)d_in[12];
  float* out = (float*)d_out;

  const int n = in_sizes[0] / D;
  const int E = in_sizes[1] / 2;
  const int nb = (n + 1023) / 1024;

  // workspace layout (~69 MB)
  char* ws = (char*)d_ws;
  size_t off = 0;
  ushort_t* P = (ushort_t*)(ws + off);  off += (size_t)NTYPES * n * D * sizeof(ushort_t);
  int* cnt    = (int*)(ws + off);       off += (size_t)n * sizeof(int);
  int* offs   = (int*)(ws + off);       off += (size_t)(n + 1) * sizeof(int);
  int* cursor = (int*)(ws + off);       off += (size_t)n * sizeof(int);
  int* loc    = (int*)(ws + off);       off += (size_t)n * sizeof(int);
  int* bsums  = (int*)(ws + off);       off += (size_t)nb * sizeof(int);
  int* total  = (int*)(ws + off);       off += 64;
  uint_t* elist = (uint_t*)(ws + off);  off += (size_t)E * sizeof(uint_t);
  int* flag   = (int*)(ws + off);       off += 64;
  ushort_t* wkh = (ushort_t*)(ws + off); off += (size_t)NTYPES * D * D * sizeof(ushort_t);
  ushort_t* wkl = (ushort_t*)(ws + off); off += (size_t)NTYPES * D * D * sizeof(ushort_t);
  ushort_t* w1h = (ushort_t*)(ws + off); off += (size_t)D * FFDIM * sizeof(ushort_t);
  ushort_t* w1l = (ushort_t*)(ws + off); off += (size_t)D * FFDIM * sizeof(ushort_t);
  ushort_t* w2h = (ushort_t*)(ws + off); off += (size_t)FFDIM * D * sizeof(ushort_t);
  ushort_t* w2l = (ushort_t*)(ws + off); off += (size_t)FFDIM * D * sizeof(ushort_t);
  (void)ws_size; (void)n_in; (void)out_size;

  // z hi/lo parked in d_out (dead before attn writes x2 there)
  ushort_t* zh = (ushort_t*)out;
  ushort_t* zl = zh + (size_t)n * D;

  // K0: mask dtype detection
  detect_kernel<<<1, 64, 0, stream>>>(masks, E, flag);

  // K1: LN1 -> z hi/lo
  ln1_kernel<<<(n + 3) / 4, 256, 0, stream>>>(x, ln1_g, ln1_b, zh, zl, n);

  // K1b: weight fragment conversion
  {
    dim3 gwk((8 * 4 * 64 + 255) / 256, NTYPES);
    conv_frag_kernel<<<gwk, 256, 0, stream>>>(Wk, wkh, wkl, D, D,
                                              (size_t)D * D, (size_t)D * D);
    dim3 gw1(((FFDIM / 16) * 4 * 64 + 255) / 256, 1);
    conv_frag_kernel<<<gw1, 256, 0, stream>>>(W1, w1h, w1l, D, FFDIM, 0, 0);
    dim3 gw2((8 * (FFDIM / 32) * 64 + 255) / 256, 1);
    conv_frag_kernel<<<gw2, 256, 0, stream>>>(W2, w2h, w2l, FFDIM, D, 0, 0);
  }

  // K2: projections
  proj_mfma_kernel<<<(n + 63) / 64, 256, 0, stream>>>(zh, zl, wkh, wkl, bk, P, n);

  // K3: CSR build by src (hierarchical scan)
  zero_kernel<<<(n + 255) / 256, 256, 0, stream>>>(cnt, n);
  hist_kernel<<<(E + 255) / 256, 256, 0, stream>>>(edges, cnt, E);
  scanA_kernel<<<nb, 256, 0, stream>>>(cnt, loc, bsums, n);
  scanB_kernel<<<1, 256, 0, stream>>>(bsums, nb, total);
  scanC_kernel<<<(n + 255) / 256, 256, 0, stream>>>(loc, bsums, total, offs, cursor, n);
  fill_kernel<<<(E + 255) / 256, 256, 0, stream>>>(edges, masks, flag, cursor, elist, E);

  // K4: attention -> out = x + attn
  attn_kernel<<<(n + 15) / 16, 256, 0, stream>>>(x, P, offs, elist, out, n);

  // K5: LN2 + FFN + residual
  ffn_mfma_kernel<<<(n + 63) / 64, 256, 0, stream>>>(w1h, w1l, w2h, w2l,
                                                     b1, b2, ln2_g, ln2_b, out, n);
}